// Round 5
// baseline (1858.181 us; speedup 1.0000x reference)
//
#include <hip/hip_runtime.h>
#include <math.h>

// DeepArcNet fused kernel, R5 = R4 structure + __launch_bounds__(256,1).
// R4 post-mortem: (256,3) capped VGPRs at 84 << ~150-float live set ->
// compiler demoted state to scratch -> 1.38 GB HBM scratch traffic @ 895
// GB/s == the whole 1.54 ms runtime. R3 proved (256,1) => zero spill.
// Structure (unchanged from R4): only h[68] (+ attn[68]/z[34] transients)
// in registers, compile-time indices only; every matvec output loop ROLLED
// (small I$-resident code), result to per-lane LDS row; cross-token
// attention reads group rows at immediate offsets; stride 35 -> conflict-
// free; item group (6 lanes) inside one wave -> no barriers needed.

#define EMBD 68
#define NTOK 6
#define HEADD 34
#define LDSW 35                    // 34 slots + 1 pad
#define LDS_ROWS (256 + 8)         // +8 pad rows: inactive-lane reads in range

__device__ __forceinline__ float dot68(const float (&h)[EMBD],
                                       const float* __restrict__ w) {
    float a0 = 0.f, a1 = 0.f, a2 = 0.f, a3 = 0.f;
#pragma unroll
    for (int e = 0; e < 68; e += 4) {
        a0 = fmaf(h[e + 0], w[e + 0], a0);
        a1 = fmaf(h[e + 1], w[e + 1], a1);
        a2 = fmaf(h[e + 2], w[e + 2], a2);
        a3 = fmaf(h[e + 3], w[e + 3], a3);
    }
    return (a0 + a1) + (a2 + a3);
}

__device__ __forceinline__ float dot34(const float (&z)[HEADD],
                                       const float* __restrict__ w) {
    float a0 = 0.f, a1 = 0.f;
#pragma unroll
    for (int e = 0; e < 34; e += 2) {
        a0 = fmaf(z[e + 0], w[e + 0], a0);
        a1 = fmaf(z[e + 1], w[e + 1], a1);
    }
    return a0 + a1;
}

__device__ __forceinline__ void ln68_ip(float (&v)[EMBD],
                                        const float* __restrict__ g,
                                        const float* __restrict__ b) {
    float s1 = 0.f;
#pragma unroll
    for (int e = 0; e < EMBD; ++e) s1 += v[e];
    const float m = s1 * (1.0f / 68.0f);
    float s2 = 0.f;
#pragma unroll
    for (int e = 0; e < EMBD; ++e) { const float d = v[e] - m; s2 = fmaf(d, d, s2); }
    const float rs = rsqrtf(s2 * (1.0f / 68.0f) + 1e-5f);
#pragma unroll
    for (int e = 0; e < EMBD; ++e) v[e] = (v[e] - m) * rs * g[e] + b[e];
}

__global__ __launch_bounds__(256, 1)
void deeparcnet_fused(const float* __restrict__ x,        // [B,6,37,5]
                      const float* __restrict__ conv_w,   // [6,1,5,5]
                      const float* __restrict__ conv_b,   // [6]
                      const float* __restrict__ lemb_w,   // [6,4]
                      const float* __restrict__ lemb_b,   // [6,4]
                      const float* __restrict__ wq,       // [2,2,34,68]
                      const float* __restrict__ wk,
                      const float* __restrict__ wv,
                      const float* __restrict__ proj_w,   // [2,68,68]
                      const float* __restrict__ proj_b,   // [2,68]
                      const float* __restrict__ ff1_w,    // [2,34,68]
                      const float* __restrict__ ff1_b,    // [2,34]
                      const float* __restrict__ ff2_w,    // [2,68,34]
                      const float* __restrict__ ff2_b,    // [2,68]
                      const float* __restrict__ ln1_g, const float* __restrict__ ln1_b,
                      const float* __restrict__ ln2_g, const float* __restrict__ ln2_b,
                      const float* __restrict__ lnf_g, const float* __restrict__ lnf_b,
                      const float* __restrict__ fc_w,     // [6,408]
                      const float* __restrict__ fc_b,     // [6]
                      float* __restrict__ out,            // [B,6]
                      int B)
{
    __shared__ float lds[LDS_ROWS * LDSW];

    const int tid  = threadIdx.x;
    const int lane = tid & 63;
    const int wid  = blockIdx.x * (blockDim.x >> 6) + (tid >> 6);
    const int sub  = lane / 6;          // item slot in wave: 0..10
    const int c    = lane - sub * 6;    // token / conv channel: 0..5
    const int item = wid * 10 + sub;
    const bool active = (sub < 10) && (item < B);
    const int it = active ? item : 0;

    float* __restrict__ myrow = lds + tid * LDSW;            // lane-private
    const float* __restrict__ grow = lds + (tid - c) * LDSW; // group base

    // ---------------- conv encode + embed + pos -> h[68] -------------------
    float h[EMBD];
    {
        float xw[25];
#pragma unroll
        for (int k = 0; k < 25; ++k) xw[k] = conv_w[c * 25 + k];
        const float cb = conv_b[c];
        const float* xp = x + (size_t)(it * 6 + c) * 185;

        const float lw0 = lemb_w[c * 4 + 0], lw1 = lemb_w[c * 4 + 1];
        const float lw2 = lemb_w[c * 4 + 2], lw3 = lemb_w[c * 4 + 3];
        const float lb0 = lemb_b[c * 4 + 0], lb1 = lemb_b[c * 4 + 1];
        const float lb2 = lemb_b[c * 4 + 2], lb3 = lemb_b[c * 4 + 3];

#pragma unroll
        for (int t = 0; t < 17; ++t) {
            float a = cb;
#pragma unroll
            for (int k = 0; k < 25; ++k) a = fmaf(xp[t * 10 + k], xw[k], a);
            const float xc = fmaxf(a, 0.0f);
            const float tf = (float)t;
            h[4 * t + 0] = fmaf(xc, lw0, lb0) + __sinf(tf);
            h[4 * t + 1] = fmaf(xc, lw1, lb1) + __sinf(tf * (1.0f / 18.0f));
            h[4 * t + 2] = fmaf(xc, lw2, lb2) + __cosf(tf);
            h[4 * t + 3] = fmaf(xc, lw3, lb3) + __cosf(tf * (1.0f / 18.0f));
        }
    }

    const float qscale = 0.16903085094570331f;  // 34^-0.5

#pragma unroll 1
    for (int l = 0; l < 2; ++l) {
        const float* Wq = wq + l * (2 * HEADD * EMBD);
        const float* Wk = wk + l * (2 * HEADD * EMBD);
        const float* Wv = wv + l * (2 * HEADD * EMBD);
        const float* Pw = proj_w + l * (EMBD * EMBD);
        const float* Pb = proj_b + l * EMBD;
        const float* W1 = ff1_w + l * (HEADD * EMBD);
        const float* b1 = ff1_b + l * HEADD;
        const float* W2 = ff2_w + l * (EMBD * HEADD);
        const float* b2 = ff2_b + l * EMBD;
        const float* g1 = ln1_g + l * EMBD; const float* e1 = ln1_b + l * EMBD;
        const float* g2 = ln2_g + l * EMBD; const float* e2 = ln2_b + l * EMBD;

        // ---- scores, head by head: k row -> LDS (rolled), then q stream ----
        float wei[2][NTOK];
#pragma unroll
        for (int hh = 0; hh < 2; ++hh) {
            const float* wkp = Wk + hh * HEADD * EMBD;
#pragma unroll 1
            for (int d = 0; d < HEADD; ++d)
                myrow[d] = dot68(h, wkp + d * EMBD);

            const float* wqp = Wq + hh * HEADD * EMBD;
            float w0 = 0.f, w1 = 0.f, w2 = 0.f, w3 = 0.f, w4 = 0.f, w5 = 0.f;
#pragma unroll 1
            for (int d = 0; d < HEADD; ++d) {
                const float qd = dot68(h, wqp + d * EMBD);
                w0 = fmaf(qd, grow[0 * LDSW + d], w0);
                w1 = fmaf(qd, grow[1 * LDSW + d], w1);
                w2 = fmaf(qd, grow[2 * LDSW + d], w2);
                w3 = fmaf(qd, grow[3 * LDSW + d], w3);
                w4 = fmaf(qd, grow[4 * LDSW + d], w4);
                w5 = fmaf(qd, grow[5 * LDSW + d], w5);
            }
            wei[hh][0] = w0; wei[hh][1] = w1; wei[hh][2] = w2;
            wei[hh][3] = w3; wei[hh][4] = w4; wei[hh][5] = w5;
        }

        // ---- softmax (q-scale folded) ----
#pragma unroll
        for (int hh = 0; hh < 2; ++hh) {
            float m = wei[hh][0] * qscale;
#pragma unroll
            for (int s = 0; s < NTOK; ++s) { wei[hh][s] *= qscale; m = fmaxf(m, wei[hh][s]); }
            float sum = 0.f;
#pragma unroll
            for (int s = 0; s < NTOK; ++s) { wei[hh][s] = __expf(wei[hh][s] - m); sum += wei[hh][s]; }
            const float r = 1.0f / sum;
#pragma unroll
            for (int s = 0; s < NTOK; ++s) wei[hh][s] *= r;
        }

        // ---- attn, head by head: v row -> LDS (rolled), gather (unrolled) --
        float attn[EMBD];
#pragma unroll
        for (int hh = 0; hh < 2; ++hh) {
            const float* wvp = Wv + hh * HEADD * EMBD;
#pragma unroll 1
            for (int d = 0; d < HEADD; ++d)
                myrow[d] = dot68(h, wvp + d * EMBD);
#pragma unroll
            for (int d = 0; d < HEADD; ++d) {
                float a = wei[hh][0] * grow[0 * LDSW + d];
                a = fmaf(wei[hh][1], grow[1 * LDSW + d], a);
                a = fmaf(wei[hh][2], grow[2 * LDSW + d], a);
                a = fmaf(wei[hh][3], grow[3 * LDSW + d], a);
                a = fmaf(wei[hh][4], grow[4 * LDSW + d], a);
                a = fmaf(wei[hh][5], grow[5 * LDSW + d], a);
                attn[hh * HEADD + d] = a;
            }
        }

        // ---- proj + residual (halves; rolled compute, unrolled reload) ----
#pragma unroll
        for (int q2 = 0; q2 < 2; ++q2) {
            const float* pw = Pw + q2 * HEADD * EMBD;
            const float* pb = Pb + q2 * HEADD;
#pragma unroll 1
            for (int p = 0; p < HEADD; ++p)
                myrow[p] = pb[p] + dot68(attn, pw + p * EMBD);
#pragma unroll
            for (int p = 0; p < HEADD; ++p) h[q2 * HEADD + p] += myrow[p];
        }
        ln68_ip(h, g1, e1);

        // ---- ff1 (relu) -> LDS, reload to z ----
#pragma unroll 1
        for (int f = 0; f < HEADD; ++f)
            myrow[f] = fmaxf(b1[f] + dot68(h, W1 + f * EMBD), 0.f);
        float z[HEADD];
#pragma unroll
        for (int f = 0; f < HEADD; ++f) z[f] = myrow[f];

        // ---- ff2 + residual (halves) ----
#pragma unroll
        for (int q2 = 0; q2 < 2; ++q2) {
            const float* w2p = W2 + q2 * HEADD * HEADD;
            const float* b2p = b2 + q2 * HEADD;
#pragma unroll 1
            for (int p = 0; p < HEADD; ++p)
                myrow[p] = b2p[p] + dot34(z, w2p + p * HEADD);
#pragma unroll
            for (int p = 0; p < HEADD; ++p) h[q2 * HEADD + p] += myrow[p];
        }
        ln68_ip(h, g2, e2);
    }

    // ---------------- final LN ----------------
    ln68_ip(h, lnf_g, lnf_b);

    // ---------------- fc head ----------------
    const int base_lane = sub * 6;
    float p[NTOK];
#pragma unroll
    for (int o = 0; o < NTOK; ++o) {
        float a = 0.f;
#pragma unroll
        for (int e = 0; e < EMBD; ++e)
            a = fmaf(h[e], fc_w[o * 408 + c * EMBD + e], a);
        p[o] = a;
    }
    float tot[NTOK];
#pragma unroll
    for (int o = 0; o < NTOK; ++o) {
        float a = 0.f;
#pragma unroll
        for (int t = 0; t < NTOK; ++t) a += __shfl(p[o], base_lane + t, 64);
        tot[o] = a + fc_b[o];
    }
    float myout = tot[0];
    if (c == 1) myout = tot[1];
    if (c == 2) myout = tot[2];
    if (c == 3) myout = tot[3];
    if (c == 4) myout = tot[4];
    if (c == 5) myout = tot[5];
    if (active) out[(size_t)item * 6 + c] = fmaxf(myout, 0.f);
}

extern "C" void kernel_launch(void* const* d_in, const int* in_sizes, int n_in,
                              void* d_out, int out_size, void* d_ws, size_t ws_size,
                              hipStream_t stream) {
    const float* x      = (const float*)d_in[0];
    const float* conv_w = (const float*)d_in[1];
    const float* conv_b = (const float*)d_in[2];
    const float* lemb_w = (const float*)d_in[3];
    const float* lemb_b = (const float*)d_in[4];
    const float* wq     = (const float*)d_in[5];
    const float* wk     = (const float*)d_in[6];
    const float* wv     = (const float*)d_in[7];
    const float* proj_w = (const float*)d_in[8];
    const float* proj_b = (const float*)d_in[9];
    const float* ff1_w  = (const float*)d_in[10];
    const float* ff1_b  = (const float*)d_in[11];
    const float* ff2_w  = (const float*)d_in[12];
    const float* ff2_b  = (const float*)d_in[13];
    const float* ln1_g  = (const float*)d_in[14];
    const float* ln1_b  = (const float*)d_in[15];
    const float* ln2_g  = (const float*)d_in[16];
    const float* ln2_b  = (const float*)d_in[17];
    const float* lnf_g  = (const float*)d_in[18];
    const float* lnf_b  = (const float*)d_in[19];
    const float* fc_w   = (const float*)d_in[20];
    const float* fc_b   = (const float*)d_in[21];
    float* out = (float*)d_out;

    const int B = in_sizes[0] / (6 * 37 * 5);           // 32768
    const int waves  = (B + 9) / 10;                    // 10 items per wave
    const int blocks = (waves + 3) / 4;                 // 4 waves per block

    deeparcnet_fused<<<blocks, 256, 0, stream>>>(
        x, conv_w, conv_b, lemb_w, lemb_b, wq, wk, wv, proj_w, proj_b,
        ff1_w, ff1_b, ff2_w, ff2_b, ln1_g, ln1_b, ln2_g, ln2_b,
        lnf_g, lnf_b, fc_w, fc_b, out, B);
}

// Round 6
// 1062.606 us; speedup vs baseline: 1.7487x; 1.7487x over previous
//
#include <hip/hip_runtime.h>
#include <math.h>

// DeepArcNet fused kernel, R6: LDS-resident weights (phase-staged).
// R5 post-mortem: zero spill but ~40 cyc/instr stall -- every wave re-fetches
// every weight from L2/HBM inside the rolled dot loops (s_load or VMEM
// broadcast either way), 3277 waves x ~190 KB redundant operand traffic.
// Fix: per block, stage each matvec's weight panel (<=18.5 KB) into LDS with
// coalesced float4 loads + barriers; rolled dots read weights as wave-uniform
// LDS broadcasts (ds_read_b128, conflict-free, ~2-4cyc) -- operands now come
// from the fastest shared tier, fetched once per block instead of per wave.
// Everything else keeps R4/R5's small-code structure: h[68] in registers
// (compile-time indices), per-lane LDS row for dynamic arrays, cross-token
// attention via group rows (6 lanes of an item always in one wave).
// LDS: rows 36.9 KB + wbuf 18.5 KB = 54.2 KB -> 2 blocks/CU.

#define EMBD 68
#define NTOK 6
#define HEADD 34
#define LDSW 35                    // 34 slots + 1 pad
#define LDS_ROWS (256 + 8)
#define WBUF 4624                  // max weight panel: 68x68 floats

__device__ __forceinline__ float dot68l(const float (&h)[EMBD],
                                        const float* w) {   // w: LDS, 16B-aligned
    float a0 = 0.f, a1 = 0.f, a2 = 0.f, a3 = 0.f;
#pragma unroll
    for (int e = 0; e < 68; e += 4) {
        const float4 wv = *(const float4*)(w + e);
        a0 = fmaf(h[e + 0], wv.x, a0);
        a1 = fmaf(h[e + 1], wv.y, a1);
        a2 = fmaf(h[e + 2], wv.z, a2);
        a3 = fmaf(h[e + 3], wv.w, a3);
    }
    return (a0 + a1) + (a2 + a3);
}

__device__ __forceinline__ float dot34l(const float (&z)[HEADD],
                                        const float* w) {   // w: LDS, 8B-aligned
    float a0 = 0.f, a1 = 0.f;
#pragma unroll
    for (int e = 0; e < 34; e += 2) {
        const float2 wv = *(const float2*)(w + e);
        a0 = fmaf(z[e + 0], wv.x, a0);
        a1 = fmaf(z[e + 1], wv.y, a1);
    }
    return a0 + a1;
}

__device__ __forceinline__ void ln68_ip(float (&v)[EMBD],
                                        const float* __restrict__ g,
                                        const float* __restrict__ b) {
    float s1 = 0.f;
#pragma unroll
    for (int e = 0; e < EMBD; ++e) s1 += v[e];
    const float m = s1 * (1.0f / 68.0f);
    float s2 = 0.f;
#pragma unroll
    for (int e = 0; e < EMBD; ++e) { const float d = v[e] - m; s2 = fmaf(d, d, s2); }
    const float rs = rsqrtf(s2 * (1.0f / 68.0f) + 1e-5f);
#pragma unroll
    for (int e = 0; e < EMBD; ++e) v[e] = (v[e] - m) * rs * g[e] + b[e];
}

__global__ __launch_bounds__(256, 1)
void deeparcnet_fused(const float* __restrict__ x,        // [B,6,37,5]
                      const float* __restrict__ conv_w,   // [6,1,5,5]
                      const float* __restrict__ conv_b,   // [6]
                      const float* __restrict__ lemb_w,   // [6,4]
                      const float* __restrict__ lemb_b,   // [6,4]
                      const float* __restrict__ wq,       // [2,2,34,68]
                      const float* __restrict__ wk,
                      const float* __restrict__ wv,
                      const float* __restrict__ proj_w,   // [2,68,68]
                      const float* __restrict__ proj_b,   // [2,68]
                      const float* __restrict__ ff1_w,    // [2,34,68]
                      const float* __restrict__ ff1_b,    // [2,34]
                      const float* __restrict__ ff2_w,    // [2,68,34]
                      const float* __restrict__ ff2_b,    // [2,68]
                      const float* __restrict__ ln1_g, const float* __restrict__ ln1_b,
                      const float* __restrict__ ln2_g, const float* __restrict__ ln2_b,
                      const float* __restrict__ lnf_g, const float* __restrict__ lnf_b,
                      const float* __restrict__ fc_w,     // [6,408]
                      const float* __restrict__ fc_b,     // [6]
                      float* __restrict__ out,            // [B,6]
                      int B)
{
    __shared__ __align__(16) float rows[LDS_ROWS * LDSW];
    __shared__ __align__(16) float wbuf[WBUF];

    const int tid  = threadIdx.x;
    const int lane = tid & 63;
    const int wid  = blockIdx.x * (blockDim.x >> 6) + (tid >> 6);
    const int sub  = lane / 6;          // item slot in wave: 0..10
    const int c    = lane - sub * 6;    // token / conv channel: 0..5
    const int item = wid * 10 + sub;
    const bool active = (sub < 10) && (item < B);
    const int it = active ? item : 0;

    float* __restrict__ myrow = rows + tid * LDSW;            // lane-private
    const float* __restrict__ grow = rows + (tid - c) * LDSW; // group base

    // stage helpers (barrier before = prev readers done; after = data ready)
    auto stage1 = [&](const float* src, int n4) {
        __syncthreads();
        float4* d4 = (float4*)wbuf;
        const float4* s4 = (const float4*)src;
#pragma unroll 1
        for (int i = tid; i < n4; i += 256) d4[i] = s4[i];
        __syncthreads();
    };
    auto stage2 = [&](const float* srcA, const float* srcB, int n4each) {
        __syncthreads();
        float4* d4 = (float4*)wbuf;
        const float4* a4 = (const float4*)srcA;
        const float4* b4 = (const float4*)srcB;
#pragma unroll 1
        for (int i = tid; i < n4each; i += 256) d4[i] = a4[i];
#pragma unroll 1
        for (int i = tid; i < n4each; i += 256) d4[n4each + i] = b4[i];
        __syncthreads();
    };

    // ---------------- conv encode + embed + pos -> h[68] -------------------
    float h[EMBD];
    {
        float xw[25];
#pragma unroll
        for (int k = 0; k < 25; ++k) xw[k] = conv_w[c * 25 + k];
        const float cb = conv_b[c];
        const float* xp = x + (size_t)(it * 6 + c) * 185;

        const float lw0 = lemb_w[c * 4 + 0], lw1 = lemb_w[c * 4 + 1];
        const float lw2 = lemb_w[c * 4 + 2], lw3 = lemb_w[c * 4 + 3];
        const float lb0 = lemb_b[c * 4 + 0], lb1 = lemb_b[c * 4 + 1];
        const float lb2 = lemb_b[c * 4 + 2], lb3 = lemb_b[c * 4 + 3];

#pragma unroll
        for (int t = 0; t < 17; ++t) {
            float a = cb;
#pragma unroll
            for (int k = 0; k < 25; ++k) a = fmaf(xp[t * 10 + k], xw[k], a);
            const float xc = fmaxf(a, 0.0f);
            const float tf = (float)t;
            h[4 * t + 0] = fmaf(xc, lw0, lb0) + __sinf(tf);
            h[4 * t + 1] = fmaf(xc, lw1, lb1) + __sinf(tf * (1.0f / 18.0f));
            h[4 * t + 2] = fmaf(xc, lw2, lb2) + __cosf(tf);
            h[4 * t + 3] = fmaf(xc, lw3, lb3) + __cosf(tf * (1.0f / 18.0f));
        }
    }

    const float qscale = 0.16903085094570331f;  // 34^-0.5

#pragma unroll 1
    for (int l = 0; l < 2; ++l) {
        const float* Wq = wq + l * (2 * HEADD * EMBD);
        const float* Wk = wk + l * (2 * HEADD * EMBD);
        const float* Wv = wv + l * (2 * HEADD * EMBD);
        const float* Pw = proj_w + l * (EMBD * EMBD);
        const float* Pb = proj_b + l * EMBD;
        const float* W1 = ff1_w + l * (HEADD * EMBD);
        const float* b1 = ff1_b + l * HEADD;
        const float* W2 = ff2_w + l * (EMBD * HEADD);
        const float* b2 = ff2_b + l * EMBD;
        const float* g1 = ln1_g + l * EMBD; const float* e1 = ln1_b + l * EMBD;
        const float* g2 = ln2_g + l * EMBD; const float* e2 = ln2_b + l * EMBD;

        // ---- scores, per head: stage Wq_h|Wk_h, k rows -> LDS, q stream ----
        float wei[2][NTOK];
#pragma unroll 1
        for (int hh = 0; hh < 2; ++hh) {
            stage2(Wq + hh * HEADD * EMBD, Wk + hh * HEADD * EMBD, 578);

#pragma unroll 1
            for (int d = 0; d < HEADD; ++d)
                myrow[d] = dot68l(h, wbuf + 2312 + d * EMBD);

            float w0 = 0.f, w1 = 0.f, w2 = 0.f, w3 = 0.f, w4 = 0.f, w5 = 0.f;
#pragma unroll 1
            for (int d = 0; d < HEADD; ++d) {
                const float qd = dot68l(h, wbuf + d * EMBD);
                w0 = fmaf(qd, grow[0 * LDSW + d], w0);
                w1 = fmaf(qd, grow[1 * LDSW + d], w1);
                w2 = fmaf(qd, grow[2 * LDSW + d], w2);
                w3 = fmaf(qd, grow[3 * LDSW + d], w3);
                w4 = fmaf(qd, grow[4 * LDSW + d], w4);
                w5 = fmaf(qd, grow[5 * LDSW + d], w5);
            }
            wei[hh][0] = w0; wei[hh][1] = w1; wei[hh][2] = w2;
            wei[hh][3] = w3; wei[hh][4] = w4; wei[hh][5] = w5;
        }

        // ---- softmax (q-scale folded) ----
#pragma unroll
        for (int hh = 0; hh < 2; ++hh) {
            float m = wei[hh][0] * qscale;
#pragma unroll
            for (int s = 0; s < NTOK; ++s) { wei[hh][s] *= qscale; m = fmaxf(m, wei[hh][s]); }
            float sum = 0.f;
#pragma unroll
            for (int s = 0; s < NTOK; ++s) { wei[hh][s] = __expf(wei[hh][s] - m); sum += wei[hh][s]; }
            const float r = 1.0f / sum;
#pragma unroll
            for (int s = 0; s < NTOK; ++s) wei[hh][s] *= r;
        }

        // ---- attn: stage Wv (both heads), v rows -> LDS, gather ----
        stage2(Wv, Wv + HEADD * EMBD, 578);
        float attn[EMBD];
#pragma unroll 1
        for (int hh = 0; hh < 2; ++hh) {
#pragma unroll 1
            for (int d = 0; d < HEADD; ++d)
                myrow[d] = dot68l(h, wbuf + hh * 2312 + d * EMBD);
#pragma unroll
            for (int d = 0; d < HEADD; ++d) {
                float a = wei[hh][0] * grow[0 * LDSW + d];
                a = fmaf(wei[hh][1], grow[1 * LDSW + d], a);
                a = fmaf(wei[hh][2], grow[2 * LDSW + d], a);
                a = fmaf(wei[hh][3], grow[3 * LDSW + d], a);
                a = fmaf(wei[hh][4], grow[4 * LDSW + d], a);
                a = fmaf(wei[hh][5], grow[5 * LDSW + d], a);
                attn[hh * HEADD + d] = a;
            }
        }

        // ---- proj + residual (stage 68x68; halves) ----
        stage1(Pw, 1156);
#pragma unroll 1
        for (int q2 = 0; q2 < 2; ++q2) {
#pragma unroll 1
            for (int p = 0; p < HEADD; ++p)
                myrow[p] = Pb[q2 * HEADD + p] + dot68l(attn, wbuf + (q2 * HEADD + p) * EMBD);
#pragma unroll
            for (int p = 0; p < HEADD; ++p) h[q2 * HEADD + p] += myrow[p];
        }
        ln68_ip(h, g1, e1);

        // ---- ff1 (relu) ----
        stage1(W1, 578);
#pragma unroll 1
        for (int f = 0; f < HEADD; ++f)
            myrow[f] = fmaxf(b1[f] + dot68l(h, wbuf + f * EMBD), 0.f);
        float z[HEADD];
#pragma unroll
        for (int f = 0; f < HEADD; ++f) z[f] = myrow[f];

        // ---- ff2 + residual ----
        stage1(W2, 578);
#pragma unroll 1
        for (int q2 = 0; q2 < 2; ++q2) {
#pragma unroll 1
            for (int p = 0; p < HEADD; ++p)
                myrow[p] = b2[q2 * HEADD + p] + dot34l(z, wbuf + (q2 * HEADD + p) * HEADD);
#pragma unroll
            for (int p = 0; p < HEADD; ++p) h[q2 * HEADD + p] += myrow[p];
        }
        ln68_ip(h, g2, e2);
    }

    // ---------------- final LN ----------------
    ln68_ip(h, lnf_g, lnf_b);

    // ---------------- fc head (stage 6x408) ----------------
    stage1(fc_w, 612);
    const int base_lane = sub * 6;
    float p[NTOK];
#pragma unroll
    for (int o = 0; o < NTOK; ++o)
        p[o] = dot68l(h, wbuf + o * 408 + c * EMBD);

    float tot[NTOK];
#pragma unroll
    for (int o = 0; o < NTOK; ++o) {
        float a = 0.f;
#pragma unroll
        for (int t = 0; t < NTOK; ++t) a += __shfl(p[o], base_lane + t, 64);
        tot[o] = a + fc_b[o];
    }
    float myout = tot[0];
    if (c == 1) myout = tot[1];
    if (c == 2) myout = tot[2];
    if (c == 3) myout = tot[3];
    if (c == 4) myout = tot[4];
    if (c == 5) myout = tot[5];
    if (active) out[(size_t)item * 6 + c] = fmaxf(myout, 0.f);
}

extern "C" void kernel_launch(void* const* d_in, const int* in_sizes, int n_in,
                              void* d_out, int out_size, void* d_ws, size_t ws_size,
                              hipStream_t stream) {
    const float* x      = (const float*)d_in[0];
    const float* conv_w = (const float*)d_in[1];
    const float* conv_b = (const float*)d_in[2];
    const float* lemb_w = (const float*)d_in[3];
    const float* lemb_b = (const float*)d_in[4];
    const float* wq     = (const float*)d_in[5];
    const float* wk     = (const float*)d_in[6];
    const float* wv     = (const float*)d_in[7];
    const float* proj_w = (const float*)d_in[8];
    const float* proj_b = (const float*)d_in[9];
    const float* ff1_w  = (const float*)d_in[10];
    const float* ff1_b  = (const float*)d_in[11];
    const float* ff2_w  = (const float*)d_in[12];
    const float* ff2_b  = (const float*)d_in[13];
    const float* ln1_g  = (const float*)d_in[14];
    const float* ln1_b  = (const float*)d_in[15];
    const float* ln2_g  = (const float*)d_in[16];
    const float* ln2_b  = (const float*)d_in[17];
    const float* lnf_g  = (const float*)d_in[18];
    const float* lnf_b  = (const float*)d_in[19];
    const float* fc_w   = (const float*)d_in[20];
    const float* fc_b   = (const float*)d_in[21];
    float* out = (float*)d_out;

    const int B = in_sizes[0] / (6 * 37 * 5);           // 32768
    const int waves  = (B + 9) / 10;                    // 10 items per wave
    const int blocks = (waves + 3) / 4;                 // 4 waves per block

    deeparcnet_fused<<<blocks, 256, 0, stream>>>(
        x, conv_w, conv_b, lemb_w, lemb_b, wq, wk, wv, proj_w, proj_b,
        ff1_w, ff1_b, ff2_w, ff2_b, ln1_g, ln1_b, ln2_g, ln2_b,
        lnf_g, lnf_b, fc_w, fc_b, out, B);
}

// Round 7
// 1054.643 us; speedup vs baseline: 1.7619x; 1.0076x over previous
//
#include <hip/hip_runtime.h>
#include <math.h>

// DeepArcNet fused kernel, R7: R6 dataflow, spill fix.
// R6 post-mortem: backend picked a ~128-VGPR occupancy target (VGPR=120)
// and spilled h[68]/attn[68] -> 850 MB scratch traffic == whole runtime.
// Fixes: (1) staging lambdas -> plain inline loops; (2) amdgpu_waves_per_eu
// (1,2) pins allocator budget at 256 VGPRs (LDS already caps at 2 blocks/CU,
// so 2 waves/EU costs nothing); (3) ff1+ff2 staged together (one barrier
// pair fewer per layer).
// Structure: h[68] in registers (compile-time indices only); per-lane LDS
// row (stride 35, conflict-free) for dynamically-indexed results; weight
// panels staged to LDS wbuf, read as wave-uniform broadcasts (ds_read_b128,
// HW broadcast = cheap); cross-token attention via 6 group rows; item's 6
// lanes always in one wave (no barrier needed for rows, only for wbuf).

#define EMBD 68
#define NTOK 6
#define HEADD 34
#define LDSW 35                    // 34 slots + 1 pad
#define LDS_ROWS 264
#define WBUF 4624                  // max panel: 68x68 floats (= 2x 34x68)

__device__ __forceinline__ float dot68l(const float (&h)[EMBD],
                                        const float* w) {   // w: LDS, 16B-aligned
    float a0 = 0.f, a1 = 0.f, a2 = 0.f, a3 = 0.f;
#pragma unroll
    for (int e = 0; e < 68; e += 4) {
        const float4 wv = *(const float4*)(w + e);
        a0 = fmaf(h[e + 0], wv.x, a0);
        a1 = fmaf(h[e + 1], wv.y, a1);
        a2 = fmaf(h[e + 2], wv.z, a2);
        a3 = fmaf(h[e + 3], wv.w, a3);
    }
    return (a0 + a1) + (a2 + a3);
}

__device__ __forceinline__ float dot34l(const float (&z)[HEADD],
                                        const float* w) {   // w: LDS, 8B-aligned
    float a0 = 0.f, a1 = 0.f;
#pragma unroll
    for (int e = 0; e < 34; e += 2) {
        const float2 wv = *(const float2*)(w + e);
        a0 = fmaf(z[e + 0], wv.x, a0);
        a1 = fmaf(z[e + 1], wv.y, a1);
    }
    return a0 + a1;
}

__device__ __forceinline__ void ln68_ip(float (&v)[EMBD],
                                        const float* __restrict__ g,
                                        const float* __restrict__ b) {
    float s1 = 0.f;
#pragma unroll
    for (int e = 0; e < EMBD; ++e) s1 += v[e];
    const float m = s1 * (1.0f / 68.0f);
    float s2 = 0.f;
#pragma unroll
    for (int e = 0; e < EMBD; ++e) { const float d = v[e] - m; s2 = fmaf(d, d, s2); }
    const float rs = rsqrtf(s2 * (1.0f / 68.0f) + 1e-5f);
#pragma unroll
    for (int e = 0; e < EMBD; ++e) v[e] = (v[e] - m) * rs * g[e] + b[e];
}

// stage: barrier, copy n4 float4s from src (and optionally src2 to second
// half), barrier.  Plain macro-free inline code, no lambdas.
#define STAGE1(SRC, N4)                                                     \
    do {                                                                    \
        __syncthreads();                                                    \
        {                                                                   \
            float4* d4 = (float4*)wbuf;                                     \
            const float4* s4 = (const float4*)(SRC);                        \
            for (int i = tid; i < (N4); i += 256) d4[i] = s4[i];            \
        }                                                                   \
        __syncthreads();                                                    \
    } while (0)

#define STAGE2(SRCA, SRCB, N4)                                              \
    do {                                                                    \
        __syncthreads();                                                    \
        {                                                                   \
            float4* d4 = (float4*)wbuf;                                     \
            const float4* a4 = (const float4*)(SRCA);                       \
            const float4* b4 = (const float4*)(SRCB);                       \
            for (int i = tid; i < (N4); i += 256) d4[i] = a4[i];            \
            for (int i = tid; i < (N4); i += 256) d4[(N4) + i] = b4[i];     \
        }                                                                   \
        __syncthreads();                                                    \
    } while (0)

__global__ void __launch_bounds__(256, 1)
__attribute__((amdgpu_waves_per_eu(1, 2)))
deeparcnet_fused(const float* __restrict__ x,        // [B,6,37,5]
                 const float* __restrict__ conv_w,   // [6,1,5,5]
                 const float* __restrict__ conv_b,   // [6]
                 const float* __restrict__ lemb_w,   // [6,4]
                 const float* __restrict__ lemb_b,   // [6,4]
                 const float* __restrict__ wq,       // [2,2,34,68]
                 const float* __restrict__ wk,
                 const float* __restrict__ wv,
                 const float* __restrict__ proj_w,   // [2,68,68]
                 const float* __restrict__ proj_b,   // [2,68]
                 const float* __restrict__ ff1_w,    // [2,34,68]
                 const float* __restrict__ ff1_b,    // [2,34]
                 const float* __restrict__ ff2_w,    // [2,68,34]
                 const float* __restrict__ ff2_b,    // [2,68]
                 const float* __restrict__ ln1_g, const float* __restrict__ ln1_b,
                 const float* __restrict__ ln2_g, const float* __restrict__ ln2_b,
                 const float* __restrict__ lnf_g, const float* __restrict__ lnf_b,
                 const float* __restrict__ fc_w,     // [6,408]
                 const float* __restrict__ fc_b,     // [6]
                 float* __restrict__ out,            // [B,6]
                 int B)
{
    __shared__ __align__(16) float rows[LDS_ROWS * LDSW];
    __shared__ __align__(16) float wbuf[WBUF];

    const int tid  = threadIdx.x;
    const int lane = tid & 63;
    const int wid  = blockIdx.x * (blockDim.x >> 6) + (tid >> 6);
    const int sub  = lane / 6;          // item slot in wave: 0..10
    const int c    = lane - sub * 6;    // token / conv channel: 0..5
    const int item = wid * 10 + sub;
    const bool active = (sub < 10) && (item < B);
    const int it = active ? item : 0;

    float* __restrict__ myrow = rows + tid * LDSW;            // lane-private
    const float* __restrict__ grow = rows + (tid - c) * LDSW; // group base

    // ---------------- conv encode + embed + pos -> h[68] -------------------
    float h[EMBD];
    {
        float xw[25];
#pragma unroll
        for (int k = 0; k < 25; ++k) xw[k] = conv_w[c * 25 + k];
        const float cb = conv_b[c];
        const float* xp = x + (size_t)(it * 6 + c) * 185;

        const float lw0 = lemb_w[c * 4 + 0], lw1 = lemb_w[c * 4 + 1];
        const float lw2 = lemb_w[c * 4 + 2], lw3 = lemb_w[c * 4 + 3];
        const float lb0 = lemb_b[c * 4 + 0], lb1 = lemb_b[c * 4 + 1];
        const float lb2 = lemb_b[c * 4 + 2], lb3 = lemb_b[c * 4 + 3];

#pragma unroll
        for (int t = 0; t < 17; ++t) {
            float a = cb;
#pragma unroll
            for (int k = 0; k < 25; ++k) a = fmaf(xp[t * 10 + k], xw[k], a);
            const float xc = fmaxf(a, 0.0f);
            const float tf = (float)t;
            h[4 * t + 0] = fmaf(xc, lw0, lb0) + __sinf(tf);
            h[4 * t + 1] = fmaf(xc, lw1, lb1) + __sinf(tf * (1.0f / 18.0f));
            h[4 * t + 2] = fmaf(xc, lw2, lb2) + __cosf(tf);
            h[4 * t + 3] = fmaf(xc, lw3, lb3) + __cosf(tf * (1.0f / 18.0f));
        }
    }

    const float qscale = 0.16903085094570331f;  // 34^-0.5

#pragma unroll 1
    for (int l = 0; l < 2; ++l) {
        const float* Wq = wq + l * (2 * HEADD * EMBD);
        const float* Wk = wk + l * (2 * HEADD * EMBD);
        const float* Wv = wv + l * (2 * HEADD * EMBD);
        const float* Pw = proj_w + l * (EMBD * EMBD);
        const float* Pb = proj_b + l * EMBD;
        const float* W1 = ff1_w + l * (HEADD * EMBD);
        const float* b1 = ff1_b + l * HEADD;
        const float* W2 = ff2_w + l * (EMBD * HEADD);
        const float* b2 = ff2_b + l * EMBD;
        const float* g1 = ln1_g + l * EMBD; const float* e1 = ln1_b + l * EMBD;
        const float* g2 = ln2_g + l * EMBD; const float* e2 = ln2_b + l * EMBD;

        // ---- scores, per head: stage Wq_h|Wk_h, k rows -> LDS, q stream ----
        float wei[2][NTOK];
#pragma unroll 1
        for (int hh = 0; hh < 2; ++hh) {
            STAGE2(Wq + hh * HEADD * EMBD, Wk + hh * HEADD * EMBD, 578);

#pragma unroll 1
            for (int d = 0; d < HEADD; ++d)
                myrow[d] = dot68l(h, wbuf + 2312 + d * EMBD);

            float w0 = 0.f, w1 = 0.f, w2 = 0.f, w3 = 0.f, w4 = 0.f, w5 = 0.f;
#pragma unroll 1
            for (int d = 0; d < HEADD; ++d) {
                const float qd = dot68l(h, wbuf + d * EMBD);
                w0 = fmaf(qd, grow[0 * LDSW + d], w0);
                w1 = fmaf(qd, grow[1 * LDSW + d], w1);
                w2 = fmaf(qd, grow[2 * LDSW + d], w2);
                w3 = fmaf(qd, grow[3 * LDSW + d], w3);
                w4 = fmaf(qd, grow[4 * LDSW + d], w4);
                w5 = fmaf(qd, grow[5 * LDSW + d], w5);
            }
            wei[hh][0] = w0; wei[hh][1] = w1; wei[hh][2] = w2;
            wei[hh][3] = w3; wei[hh][4] = w4; wei[hh][5] = w5;
        }

        // ---- softmax (q-scale folded) ----
#pragma unroll
        for (int hh = 0; hh < 2; ++hh) {
            float m = wei[hh][0] * qscale;
#pragma unroll
            for (int s = 0; s < NTOK; ++s) { wei[hh][s] *= qscale; m = fmaxf(m, wei[hh][s]); }
            float sum = 0.f;
#pragma unroll
            for (int s = 0; s < NTOK; ++s) { wei[hh][s] = __expf(wei[hh][s] - m); sum += wei[hh][s]; }
            const float r = 1.0f / sum;
#pragma unroll
            for (int s = 0; s < NTOK; ++s) wei[hh][s] *= r;
        }

        // ---- attn: stage Wv (both heads), v rows -> LDS, gather ----
        STAGE2(Wv, Wv + HEADD * EMBD, 578);
        float attn[EMBD];
#pragma unroll 1
        for (int hh = 0; hh < 2; ++hh) {
#pragma unroll 1
            for (int d = 0; d < HEADD; ++d)
                myrow[d] = dot68l(h, wbuf + hh * 2312 + d * EMBD);
#pragma unroll
            for (int d = 0; d < HEADD; ++d) {
                float a = wei[hh][0] * grow[0 * LDSW + d];
                a = fmaf(wei[hh][1], grow[1 * LDSW + d], a);
                a = fmaf(wei[hh][2], grow[2 * LDSW + d], a);
                a = fmaf(wei[hh][3], grow[3 * LDSW + d], a);
                a = fmaf(wei[hh][4], grow[4 * LDSW + d], a);
                a = fmaf(wei[hh][5], grow[5 * LDSW + d], a);
                attn[hh * HEADD + d] = a;
            }
        }

        // ---- proj + residual (stage 68x68; halves) ----
        STAGE1(Pw, 1156);
#pragma unroll 1
        for (int q2 = 0; q2 < 2; ++q2) {
#pragma unroll 1
            for (int p = 0; p < HEADD; ++p)
                myrow[p] = Pb[q2 * HEADD + p] + dot68l(attn, wbuf + (q2 * HEADD + p) * EMBD);
#pragma unroll
            for (int p = 0; p < HEADD; ++p) h[q2 * HEADD + p] += myrow[p];
        }
        ln68_ip(h, g1, e1);

        // ---- ff1 + ff2 (one staging: W1 -> [0,2312), W2 -> [2312,4624)) ----
        STAGE2(W1, W2, 578);
#pragma unroll 1
        for (int f = 0; f < HEADD; ++f)
            myrow[f] = fmaxf(b1[f] + dot68l(h, wbuf + f * EMBD), 0.f);
        float z[HEADD];
#pragma unroll
        for (int f = 0; f < HEADD; ++f) z[f] = myrow[f];

#pragma unroll 1
        for (int q2 = 0; q2 < 2; ++q2) {
#pragma unroll 1
            for (int p = 0; p < HEADD; ++p)
                myrow[p] = b2[q2 * HEADD + p] + dot34l(z, wbuf + 2312 + (q2 * HEADD + p) * HEADD);
#pragma unroll
            for (int p = 0; p < HEADD; ++p) h[q2 * HEADD + p] += myrow[p];
        }
        ln68_ip(h, g2, e2);
    }

    // ---------------- final LN ----------------
    ln68_ip(h, lnf_g, lnf_b);

    // ---------------- fc head (stage 6x408) ----------------
    STAGE1(fc_w, 612);
    const int base_lane = sub * 6;
    float p[NTOK];
#pragma unroll
    for (int o = 0; o < NTOK; ++o)
        p[o] = dot68l(h, wbuf + o * 408 + c * EMBD);

    float tot[NTOK];
#pragma unroll
    for (int o = 0; o < NTOK; ++o) {
        float a = 0.f;
#pragma unroll
        for (int t = 0; t < NTOK; ++t) a += __shfl(p[o], base_lane + t, 64);
        tot[o] = a + fc_b[o];
    }
    float myout = tot[0];
    if (c == 1) myout = tot[1];
    if (c == 2) myout = tot[2];
    if (c == 3) myout = tot[3];
    if (c == 4) myout = tot[4];
    if (c == 5) myout = tot[5];
    if (active) out[(size_t)item * 6 + c] = fmaxf(myout, 0.f);
}

extern "C" void kernel_launch(void* const* d_in, const int* in_sizes, int n_in,
                              void* d_out, int out_size, void* d_ws, size_t ws_size,
                              hipStream_t stream) {
    const float* x      = (const float*)d_in[0];
    const float* conv_w = (const float*)d_in[1];
    const float* conv_b = (const float*)d_in[2];
    const float* lemb_w = (const float*)d_in[3];
    const float* lemb_b = (const float*)d_in[4];
    const float* wq     = (const float*)d_in[5];
    const float* wk     = (const float*)d_in[6];
    const float* wv     = (const float*)d_in[7];
    const float* proj_w = (const float*)d_in[8];
    const float* proj_b = (const float*)d_in[9];
    const float* ff1_w  = (const float*)d_in[10];
    const float* ff1_b  = (const float*)d_in[11];
    const float* ff2_w  = (const float*)d_in[12];
    const float* ff2_b  = (const float*)d_in[13];
    const float* ln1_g  = (const float*)d_in[14];
    const float* ln1_b  = (const float*)d_in[15];
    const float* ln2_g  = (const float*)d_in[16];
    const float* ln2_b  = (const float*)d_in[17];
    const float* lnf_g  = (const float*)d_in[18];
    const float* lnf_b  = (const float*)d_in[19];
    const float* fc_w   = (const float*)d_in[20];
    const float* fc_b   = (const float*)d_in[21];
    float* out = (float*)d_out;

    const int B = in_sizes[0] / (6 * 37 * 5);           // 32768
    const int waves  = (B + 9) / 10;                    // 10 items per wave
    const int blocks = (waves + 3) / 4;                 // 4 waves per block

    deeparcnet_fused<<<blocks, 256, 0, stream>>>(
        x, conv_w, conv_b, lemb_w, lemb_b, wq, wk, wv, proj_w, proj_b,
        ff1_w, ff1_b, ff2_w, ff2_b, ln1_g, ln1_b, ln2_g, ln2_b,
        lnf_g, lnf_b, fc_w, fc_b, out, B);
}